// Round 2
// baseline (400.070 us; speedup 1.0000x reference)
//
#include <hip/hip_runtime.h>
#include <math.h>

#define BB 32
#define NN 128
#define DD 64
#define EE (NN*NN)          // 16384
#define EPSI 1e-5f
#define CH 8                // edge channels per block in k_edge

// ---------------------------------------------------------------------------
// k_fold: M[d][k] = sum_o Wp[d][128+o] * We[o][k]   (fold fc_e into fc_proj)
//         w[k]    = sum_o Wa[128+o]    * We[o][k]   (fold fc_e into attn_fc)
__global__ void k_fold(const float* __restrict__ Wp, const float* __restrict__ We,
                       const float* __restrict__ Wa,
                       float* __restrict__ M, float* __restrict__ w)
{
    int t = blockIdx.x * 256 + threadIdx.x;   // 0..4095
    int d = t >> 6, k = t & 63;
    float acc = 0.f;
    for (int o = 0; o < DD; ++o)
        acc += Wp[d*192 + 128 + o] * We[o*DD + k];
    M[d*DD + k] = acc;
    if (d == 0) {
        float aw = 0.f;
        for (int o = 0; o < DD; ++o)
            aw += Wa[128 + o] * We[o*DD + k];
        w[k] = aw;
    }
}

// ---------------------------------------------------------------------------
// k_node: per (b,n) row: z_h = x @ Wh^T ; P_src = z_h @ Wp[:, :64]^T ;
//         P_dst = z_h @ Wp[:, 64:128]^T ; s = z_h . Wa[:64] ; t = z_h . Wa[64:128]
__global__ void k_node(const float* __restrict__ x, const float* __restrict__ Wh,
                       const float* __restrict__ Wp, const float* __restrict__ Wa,
                       float* __restrict__ zh, float* __restrict__ Ps,
                       float* __restrict__ Pd, float* __restrict__ sO,
                       float* __restrict__ tO)
{
    int row = blockIdx.x;          // b*N + n
    int d = threadIdx.x;           // 0..63
    __shared__ float xr[DD];
    __shared__ float zr[DD];
    xr[d] = x[row*DD + d];
    __syncthreads();
    float acc = 0.f;
#pragma unroll
    for (int k = 0; k < DD; ++k) acc += xr[k] * Wh[d*DD + k];
    zr[d] = acc;
    zh[row*DD + d] = acc;
    __syncthreads();
    float a0 = 0.f, a1 = 0.f;
#pragma unroll
    for (int o = 0; o < DD; ++o) {
        float z = zr[o];
        a0 += Wp[d*192 + o]      * z;
        a1 += Wp[d*192 + 64 + o] * z;
    }
    Ps[row*DD + d] = a0;
    Pd[row*DD + d] = a1;
    float sv = zr[d] * Wa[d];
    float tv = zr[d] * Wa[64 + d];
#pragma unroll
    for (int off = 32; off; off >>= 1) {
        sv += __shfl_xor(sv, off);
        tv += __shfl_xor(tv, off);
    }
    if (d == 0) { sO[row] = sv; tO[row] = tv; }
}

// ---------------------------------------------------------------------------
// k_edge v2: fused  z = edge @ M^T + P_src[j] + P_dst[i]  -> BN(per-e) -> ELU
//            side output u[b,e] = edge . w
// CH=8 channels/block, 256 threads. Thread (tr=t>>3, tc=t&7) computes
// 8 rows x 8 cols; its 8 rows share one channel e = e0 + (tr>>2),
// batches b = 8*(tr&3) + m. A is read straight from global (float4 along k,
// 8-way lane-dup merges in the coalescer); only B^T lives in LDS (17.7 KB).
// Channel <-> one half-wave (32 lanes): BN reduce is shfl_xor over 32.
__global__ __launch_bounds__(256) void k_edge(
    const float* __restrict__ ein,   // (B,E,D)
    const float* __restrict__ M,     // (D,D)
    const float* __restrict__ wvec,  // (D)
    const float* __restrict__ Ps,    // (B,N,D)
    const float* __restrict__ Pd,    // (B,N,D)
    const float* __restrict__ ge, const float* __restrict__ be,
    float* __restrict__ eout, float* __restrict__ uout)
{
    __shared__ float Bt[64][68];   // Bt[k][d] = M[d][k]
    __shared__ float wl[64];
    const int t  = threadIdx.x;
    const int e0 = blockIdx.x * CH;

    // ---- stage Bt (transpose M) + w ----
    {
        int d0 = t >> 4;          // 0..15
        int q  = t & 15;          // float4 index along k
        for (int d = d0; d < 64; d += 16) {
            const float4 mv = reinterpret_cast<const float4*>(M)[d*16 + q];
            Bt[q*4+0][d] = mv.x;
            Bt[q*4+1][d] = mv.y;
            Bt[q*4+2][d] = mv.z;
            Bt[q*4+3][d] = mv.w;
        }
        if (t < 64) wl[t] = wvec[t];
    }
    __syncthreads();

    const int tr = t >> 3;            // 0..31
    const int tc = t & 7;             // cols 8*tc .. 8*tc+7
    const int e  = e0 + (tr >> 2);    // this thread's channel
    const int b0 = (tr & 3) * 8;      // batches b0..b0+7
    const int gi = e >> 7, gj = e & 127;

    float acc[8][8];
    float uacc[8];
    // ---- init with P_src[b,j] + P_dst[b,i] ----
#pragma unroll
    for (int m = 0; m < 8; ++m) {
        uacc[m] = 0.f;
        int b = b0 + m;
        const float4* ps = reinterpret_cast<const float4*>(Ps + (b*NN + gj)*DD + tc*8);
        const float4* pd = reinterpret_cast<const float4*>(Pd + (b*NN + gi)*DD + tc*8);
        float4 v0 = ps[0], v1 = ps[1];
        float4 w0 = pd[0], w1 = pd[1];
        acc[m][0] = v0.x + w0.x; acc[m][1] = v0.y + w0.y;
        acc[m][2] = v0.z + w0.z; acc[m][3] = v0.w + w0.w;
        acc[m][4] = v1.x + w1.x; acc[m][5] = v1.y + w1.y;
        acc[m][6] = v1.z + w1.z; acc[m][7] = v1.w + w1.w;
    }

    // per-row global base (element index of row start)
    const float* arow[8];
#pragma unroll
    for (int m = 0; m < 8; ++m)
        arow[m] = ein + ((size_t)((b0 + m)*EE + e))*DD;

    // ---- GEMM k-loop: A from global, B from LDS ----
#pragma unroll 4
    for (int k = 0; k < 64; k += 4) {
        float4 a[8];
#pragma unroll
        for (int m = 0; m < 8; ++m)
            a[m] = *reinterpret_cast<const float4*>(arow[m] + k);
        const float4 wk = *reinterpret_cast<const float4*>(&wl[k]);
#pragma unroll
        for (int m = 0; m < 8; ++m)
            uacc[m] += a[m].x*wk.x + a[m].y*wk.y + a[m].z*wk.z + a[m].w*wk.w;
#pragma unroll
        for (int kk = 0; kk < 4; ++kk) {
            float4 bv0 = *reinterpret_cast<const float4*>(&Bt[k+kk][tc*8]);
            float4 bv1 = *reinterpret_cast<const float4*>(&Bt[k+kk][tc*8+4]);
#pragma unroll
            for (int m = 0; m < 8; ++m) {
                float av = (kk == 0) ? a[m].x : (kk == 1) ? a[m].y : (kk == 2) ? a[m].z : a[m].w;
                acc[m][0] += av*bv0.x; acc[m][1] += av*bv0.y;
                acc[m][2] += av*bv0.z; acc[m][3] += av*bv0.w;
                acc[m][4] += av*bv1.x; acc[m][5] += av*bv1.y;
                acc[m][6] += av*bv1.z; acc[m][7] += av*bv1.w;
            }
        }
    }

    // ---- u store (all tc lanes computed identical uacc; one writes) ----
    if (tc == 0) {
#pragma unroll
        for (int m = 0; m < 8; ++m)
            uout[(b0 + m)*EE + e] = uacc[m];
    }

    // ---- BN stats: channel = half-wave (32 lanes), 2048 elems ----
    float s1 = 0.f, s2 = 0.f;
#pragma unroll
    for (int m = 0; m < 8; ++m)
#pragma unroll
        for (int c = 0; c < 8; ++c) { float v = acc[m][c]; s1 += v; s2 += v*v; }
#pragma unroll
    for (int off = 1; off < 32; off <<= 1) {
        s1 += __shfl_xor(s1, off);
        s2 += __shfl_xor(s2, off);
    }
    float mean  = s1 * (1.f/2048.f);
    float var   = s2 * (1.f/2048.f) - mean*mean;
    float scale = ge[e] * rsqrtf(var + EPSI);
    float shift = be[e] - mean*scale;

    // ---- normalize + ELU + store ----
#pragma unroll
    for (int m = 0; m < 8; ++m) {
        float o[8];
#pragma unroll
        for (int c = 0; c < 8; ++c) {
            float v = acc[m][c]*scale + shift;
            o[c] = v > 0.f ? v : expm1f(v);
        }
        float4* dst = reinterpret_cast<float4*>(eout + ((size_t)((b0 + m)*EE + e))*DD + tc*8);
        dst[0] = make_float4(o[0], o[1], o[2], o[3]);
        dst[1] = make_float4(o[4], o[5], o[6], o[7]);
    }
}

// ---------------------------------------------------------------------------
// k_attn: per (b,i): logits = lrelu(s[j] + t[i] + u[b,i*N+j]) -> softmax over j
//         agg[b,i,:] = sum_j attn_j * zh[b,j,:]
__global__ void k_attn(const float* __restrict__ sI, const float* __restrict__ tI,
                       const float* __restrict__ u, const float* __restrict__ zh,
                       float* __restrict__ agg)
{
    int blk = blockIdx.x; int b = blk >> 7, i = blk & 127;
    int l = threadIdx.x;
    __shared__ float at[NN];
    float ti = tI[blk];
    float l0 = sI[b*NN + l]      + ti + u[b*EE + i*NN + l];
    float l1 = sI[b*NN + l + 64] + ti + u[b*EE + i*NN + l + 64];
    l0 = l0 >= 0.f ? l0 : 0.01f*l0;
    l1 = l1 >= 0.f ? l1 : 0.01f*l1;
    float mx = fmaxf(l0, l1);
#pragma unroll
    for (int off = 32; off; off >>= 1) mx = fmaxf(mx, __shfl_xor(mx, off));
    float e0 = expf(l0 - mx), e1 = expf(l1 - mx);
    float sm = e0 + e1;
#pragma unroll
    for (int off = 32; off; off >>= 1) sm += __shfl_xor(sm, off);
    float inv = 1.f / sm;
    at[l]      = e0 * inv;
    at[l + 64] = e1 * inv;
    __syncthreads();
    float acc = 0.f;
    for (int j = 0; j < NN; ++j) acc += at[j] * zh[(b*NN + j)*DD + l];
    agg[(b*NN + i)*DD + l] = acc;
}

// ---------------------------------------------------------------------------
// k_vbn: vertex BN (channel i over b,d) + residual + ELU
__global__ void k_vbn(const float* __restrict__ agg, const float* __restrict__ xres,
                      const float* __restrict__ gv, const float* __restrict__ bv,
                      float* __restrict__ xout)
{
    int i = blockIdx.x, t = threadIdx.x;
    float vals[8];
    float s1 = 0.f, s2 = 0.f;
#pragma unroll
    for (int q = 0; q < 8; ++q) {
        int m = t + 256*q; int b = m >> 6, d = m & 63;
        float v = agg[(b*NN + i)*DD + d];
        vals[q] = v; s1 += v; s2 += v*v;
    }
#pragma unroll
    for (int off = 1; off < 64; off <<= 1) {
        s1 += __shfl_xor(s1, off);
        s2 += __shfl_xor(s2, off);
    }
    __shared__ float r1[4], r2[4];
    int wv = t >> 6;
    if ((t & 63) == 0) { r1[wv] = s1; r2[wv] = s2; }
    __syncthreads();
    s1 = r1[0] + r1[1] + r1[2] + r1[3];
    s2 = r2[0] + r2[1] + r2[2] + r2[3];
    float mean  = s1 * (1.f/2048.f);
    float var   = s2 * (1.f/2048.f) - mean*mean;
    float scale = gv[i] * rsqrtf(var + EPSI);
    float shift = bv[i] - mean*scale;
#pragma unroll
    for (int q = 0; q < 8; ++q) {
        int m = t + 256*q; int b = m >> 6, d = m & 63;
        float v = vals[q]*scale + shift + xres[(b*NN + i)*DD + d];
        xout[(b*NN + i)*DD + d] = v > 0.f ? v : expm1f(v);
    }
}

// ---------------------------------------------------------------------------
extern "C" void kernel_launch(void* const* d_in, const int* in_sizes, int n_in,
                              void* d_out, int out_size, void* d_ws, size_t ws_size,
                              hipStream_t stream)
{
    const float* x    = (const float*)d_in[0];
    const float* edge = (const float*)d_in[1];
    const float* Wh1  = (const float*)d_in[2];
    const float* We1  = (const float*)d_in[3];
    const float* Wp1  = (const float*)d_in[4];
    const float* Wa1  = (const float*)d_in[5];
    const float* Wh2  = (const float*)d_in[6];
    const float* We2  = (const float*)d_in[7];
    const float* Wp2  = (const float*)d_in[8];
    const float* Wa2  = (const float*)d_in[9];
    const float* gv1  = (const float*)d_in[10];
    const float* bv1  = (const float*)d_in[11];
    const float* ge1  = (const float*)d_in[12];
    const float* be1  = (const float*)d_in[13];
    const float* gv2  = (const float*)d_in[14];
    const float* bv2  = (const float*)d_in[15];
    const float* ge2  = (const float*)d_in[16];
    const float* be2  = (const float*)d_in[17];

    float* xout = (float*)d_out;                    // (B,N,D)
    float* eout = (float*)d_out + BB*NN*DD;         // (B,E,D) — also layer-1 intermediate

    float* ws  = (float*)d_ws;
    float* M   = ws;  ws += DD*DD;
    float* wv  = ws;  ws += DD;
    float* zh  = ws;  ws += BB*NN*DD;
    float* Ps  = ws;  ws += BB*NN*DD;
    float* Pd  = ws;  ws += BB*NN*DD;
    float* sb  = ws;  ws += BB*NN;
    float* tb  = ws;  ws += BB*NN;
    float* ub  = ws;  ws += BB*EE;
    float* agg = ws;  ws += BB*NN*DD;
    float* x1  = ws;  ws += BB*NN*DD;   // total ~7.4 MB

    // ----- layer 1 -----
    k_fold<<<16, 256, 0, stream>>>(Wp1, We1, Wa1, M, wv);
    k_node<<<BB*NN, 64, 0, stream>>>(x, Wh1, Wp1, Wa1, zh, Ps, Pd, sb, tb);
    k_edge<<<EE/CH, 256, 0, stream>>>(edge, M, wv, Ps, Pd, ge1, be1, eout, ub);
    k_attn<<<BB*NN, 64, 0, stream>>>(sb, tb, ub, zh, agg);
    k_vbn<<<NN, 256, 0, stream>>>(agg, x, gv1, bv1, x1);
    // ----- layer 2 (edge path reads/writes eout in place; reads precede writes
    //               within the owning half-wave, so in-place is safe) -----
    k_fold<<<16, 256, 0, stream>>>(Wp2, We2, Wa2, M, wv);
    k_node<<<BB*NN, 64, 0, stream>>>(x1, Wh2, Wp2, Wa2, zh, Ps, Pd, sb, tb);
    k_edge<<<EE/CH, 256, 0, stream>>>(eout, M, wv, Ps, Pd, ge2, be2, eout, ub);
    k_attn<<<BB*NN, 64, 0, stream>>>(sb, tb, ub, zh, agg);
    k_vbn<<<NN, 256, 0, stream>>>(agg, x1, gv2, bv2, xout);
}

// Round 3
// 274.078 us; speedup vs baseline: 1.4597x; 1.4597x over previous
//
#include <hip/hip_runtime.h>
#include <math.h>

#define BB 32
#define NN 128
#define DD 64
#define EE (NN*NN)          // 16384
#define EPSI 1e-5f
#define CH 4                // edge channels per k_edge block

typedef __attribute__((ext_vector_type(8))) short bf16x8;   // 8 bf16 (4 VGPRs)
typedef __attribute__((ext_vector_type(4))) float f32x4;

__device__ __forceinline__ short f2bf(float f) {
    union { float f; unsigned u; } v; v.f = f;
    unsigned u = v.u;
    unsigned r = (u + 0x7FFFu + ((u >> 16) & 1u)) >> 16;    // RNE
    return (short)r;
}
__device__ __forceinline__ float dot4(float4 a, float4 b) {
    return a.x*b.x + a.y*b.y + a.z*b.z + a.w*b.w;
}

// ---------------------------------------------------------------------------
// k_fold: M[d][k] = sum_o Wp[d][128+o] * We[o][k]   (fold fc_e into fc_proj)
//         w[k]    = sum_o Wa[128+o]    * We[o][k]   (fold fc_e into attn_fc)
__global__ void k_fold(const float* __restrict__ Wp, const float* __restrict__ We,
                       const float* __restrict__ Wa,
                       float* __restrict__ M, float* __restrict__ w)
{
    int t = blockIdx.x * 256 + threadIdx.x;   // 0..4095
    int d = t >> 6, k = t & 63;
    float acc = 0.f;
    for (int o = 0; o < DD; ++o)
        acc += Wp[d*192 + 128 + o] * We[o*DD + k];
    M[d*DD + k] = acc;
    if (d == 0) {
        float aw = 0.f;
        for (int o = 0; o < DD; ++o)
            aw += Wa[128 + o] * We[o*DD + k];
        w[k] = aw;
    }
}

// ---------------------------------------------------------------------------
// k_node: per (b,n) row: z_h = x @ Wh^T ; P_src = z_h @ Wp[:, :64]^T ;
//         P_dst = z_h @ Wp[:, 64:128]^T ; s = z_h . Wa[:64] ; t = z_h . Wa[64:128]
__global__ void k_node(const float* __restrict__ x, const float* __restrict__ Wh,
                       const float* __restrict__ Wp, const float* __restrict__ Wa,
                       float* __restrict__ zh, float* __restrict__ Ps,
                       float* __restrict__ Pd, float* __restrict__ sO,
                       float* __restrict__ tO)
{
    int row = blockIdx.x;          // b*N + n
    int d = threadIdx.x;           // 0..63
    __shared__ float xr[DD];
    __shared__ float zr[DD];
    xr[d] = x[row*DD + d];
    __syncthreads();
    float acc = 0.f;
#pragma unroll
    for (int k = 0; k < DD; ++k) acc += xr[k] * Wh[d*DD + k];
    zr[d] = acc;
    zh[row*DD + d] = acc;
    __syncthreads();
    float a0 = 0.f, a1 = 0.f;
#pragma unroll
    for (int o = 0; o < DD; ++o) {
        float z = zr[o];
        a0 += Wp[d*192 + o]      * z;
        a1 += Wp[d*192 + 64 + o] * z;
    }
    Ps[row*DD + d] = a0;
    Pd[row*DD + d] = a1;
    float sv = zr[d] * Wa[d];
    float tv = zr[d] * Wa[64 + d];
#pragma unroll
    for (int off = 32; off; off >>= 1) {
        sv += __shfl_xor(sv, off);
        tv += __shfl_xor(tv, off);
    }
    if (d == 0) { sO[row] = sv; tO[row] = tv; }
}

// ---------------------------------------------------------------------------
// k_edge v3 (bf16 MFMA):  z = edge @ M^T + Ps[b,j] + Pd[b,i] -> BN(per-e) -> ELU
//                         side output u[b,e] = edge . w  (fp32)
// Block = 128 threads (2 waves) = 128 rows x 64 cols, rows r -> (b=r>>2, e=e0+(r&3)).
// A loaded straight from global in MFMA fragment layout; B (=M^T) + w in registers.
// Epilogue repacks C-fragments through LDS for coalesced P-add / BN / store.
__global__ __launch_bounds__(128) void k_edge(
    const float* __restrict__ ein,   // (B,E,D)
    const float* __restrict__ M,     // (D,D)
    const float* __restrict__ wvec,  // (D)
    const float* __restrict__ Ps,    // (B,N,D)
    const float* __restrict__ Pd,    // (B,N,D)
    const float* __restrict__ ge, const float* __restrict__ be,
    float* __restrict__ eout, float* __restrict__ uout)
{
    __shared__ float zl[128][68];    // padded: 2-way-max bank aliasing (free)
    __shared__ float red[2][4][2];   // [wave][ch][sum,sumsq]
    __shared__ float bcast[4][2];    // [ch][scale,shift]

    const int t  = threadIdx.x;
    const int l  = t & 63;           // lane
    const int w  = t >> 6;           // wave 0/1
    const int lr = l & 15;           // A-row / B-col / C-col within tile
    const int lg = l >> 4;           // k-group (inputs) / row-group (C)
    const int e0 = blockIdx.x * CH;
    const int i0 = e0 >> 7;          // node i shared by this block's channels
    const int j0 = e0 & 127;

    // ---- B fragments (full M^T as bf16) + w fragment (fp32), in registers ----
    bf16x8 bfr[4][2];
#pragma unroll
    for (int n = 0; n < 4; ++n) {
        const int d = 16*n + lr;
#pragma unroll
        for (int s = 0; s < 2; ++s) {
            const float4 lo = *reinterpret_cast<const float4*>(M + d*64 + s*32 + lg*8);
            const float4 hi = *reinterpret_cast<const float4*>(M + d*64 + s*32 + lg*8 + 4);
            bfr[n][s][0] = f2bf(lo.x); bfr[n][s][1] = f2bf(lo.y);
            bfr[n][s][2] = f2bf(lo.z); bfr[n][s][3] = f2bf(lo.w);
            bfr[n][s][4] = f2bf(hi.x); bfr[n][s][5] = f2bf(hi.y);
            bfr[n][s][6] = f2bf(hi.z); bfr[n][s][7] = f2bf(hi.w);
        }
    }
    float4 wlo[2], whi[2];
#pragma unroll
    for (int s = 0; s < 2; ++s) {
        wlo[s] = *reinterpret_cast<const float4*>(wvec + s*32 + lg*8);
        whi[s] = *reinterpret_cast<const float4*>(wvec + s*32 + lg*8 + 4);
    }

    f32x4 acc[4][4];
#pragma unroll
    for (int m = 0; m < 4; ++m)
#pragma unroll
        for (int n = 0; n < 4; ++n)
            acc[m][n] = (f32x4){0.f, 0.f, 0.f, 0.f};

    // ---- GEMM + u: wave w owns rows 64w..64w+63 ----
#pragma unroll
    for (int m = 0; m < 4; ++m) {
        const int R = 64*w + 16*m + lr;
        const int b = R >> 2, e = e0 + (R & 3);
        const float* rowp = ein + ((size_t)(b*EE + e))*DD;
        const float4 a0lo = *reinterpret_cast<const float4*>(rowp +      lg*8);
        const float4 a0hi = *reinterpret_cast<const float4*>(rowp +      lg*8 + 4);
        const float4 a1lo = *reinterpret_cast<const float4*>(rowp + 32 + lg*8);
        const float4 a1hi = *reinterpret_cast<const float4*>(rowp + 32 + lg*8 + 4);
        // attention logit partial in fp32
        float up = dot4(a0lo, wlo[0]) + dot4(a0hi, whi[0])
                 + dot4(a1lo, wlo[1]) + dot4(a1hi, whi[1]);
        up += __shfl_xor(up, 16);
        up += __shfl_xor(up, 32);
        if (lg == 0) uout[b*EE + e] = up;
        // convert A to bf16 fragments
        bf16x8 a0, a1;
        a0[0]=f2bf(a0lo.x); a0[1]=f2bf(a0lo.y); a0[2]=f2bf(a0lo.z); a0[3]=f2bf(a0lo.w);
        a0[4]=f2bf(a0hi.x); a0[5]=f2bf(a0hi.y); a0[6]=f2bf(a0hi.z); a0[7]=f2bf(a0hi.w);
        a1[0]=f2bf(a1lo.x); a1[1]=f2bf(a1lo.y); a1[2]=f2bf(a1lo.z); a1[3]=f2bf(a1lo.w);
        a1[4]=f2bf(a1hi.x); a1[5]=f2bf(a1hi.y); a1[6]=f2bf(a1hi.z); a1[7]=f2bf(a1hi.w);
#pragma unroll
        for (int n = 0; n < 4; ++n) {
            acc[m][n] = __builtin_amdgcn_mfma_f32_16x16x32_bf16(a0, bfr[n][0], acc[m][n], 0, 0, 0);
            acc[m][n] = __builtin_amdgcn_mfma_f32_16x16x32_bf16(a1, bfr[n][1], acc[m][n], 0, 0, 0);
        }
    }

    // ---- C fragments -> LDS (row = 16m + 4*lg + q, col = 16n + lr) ----
#pragma unroll
    for (int m = 0; m < 4; ++m)
#pragma unroll
        for (int n = 0; n < 4; ++n)
#pragma unroll
            for (int q = 0; q < 4; ++q)
                zl[64*w + 16*m + 4*lg + q][16*n + lr] = acc[m][n][q];
    __syncthreads();

    // ---- pass 1: z += Ps + Pd (coalesced), BN stats (channel == 16-lane group) ----
    const int q4 = (t & 15) * 4;     // float col
    float s1 = 0.f, s2 = 0.f;
#pragma unroll
    for (int it = 0; it < 16; ++it) {
        const int r = (t >> 4) + 8*it;
        const int b = r >> 2;
        const int gj = j0 + (r & 3);
        float4 z = *reinterpret_cast<float4*>(&zl[r][q4]);
        const float4 ps = *reinterpret_cast<const float4*>(Ps + (b*NN + gj)*DD + q4);
        const float4 pd = *reinterpret_cast<const float4*>(Pd + (b*NN + i0)*DD + q4);
        z.x += ps.x + pd.x; z.y += ps.y + pd.y;
        z.z += ps.z + pd.z; z.w += ps.w + pd.w;
        s1 += z.x + z.y + z.z + z.w;
        s2 += z.x*z.x + z.y*z.y + z.z*z.z + z.w*z.w;
        *reinterpret_cast<float4*>(&zl[r][q4]) = z;
    }
#pragma unroll
    for (int off = 1; off < 16; off <<= 1) {
        s1 += __shfl_xor(s1, off);
        s2 += __shfl_xor(s2, off);
    }
    if (lr == 0) { red[w][lg][0] = s1; red[w][lg][1] = s2; }
    __syncthreads();
    if (t < CH) {
        float a1 = red[0][t][0] + red[1][t][0];
        float a2 = red[0][t][1] + red[1][t][1];
        float mean = a1 * (1.f/2048.f);
        float var  = a2 * (1.f/2048.f) - mean*mean;
        float sc = ge[e0 + t] * rsqrtf(var + EPSI);
        bcast[t][0] = sc;
        bcast[t][1] = be[e0 + t] - mean*sc;
    }
    __syncthreads();

    // ---- pass 2: normalize + ELU + coalesced store ----
#pragma unroll
    for (int it = 0; it < 16; ++it) {
        const int r = (t >> 4) + 8*it;
        const int b = r >> 2, e = e0 + (r & 3);
        const float sc = bcast[r & 3][0], sh = bcast[r & 3][1];
        float4 z = *reinterpret_cast<float4*>(&zl[r][q4]);
        z.x = z.x*sc + sh; z.y = z.y*sc + sh;
        z.z = z.z*sc + sh; z.w = z.w*sc + sh;
        z.x = z.x > 0.f ? z.x : expm1f(z.x);
        z.y = z.y > 0.f ? z.y : expm1f(z.y);
        z.z = z.z > 0.f ? z.z : expm1f(z.z);
        z.w = z.w > 0.f ? z.w : expm1f(z.w);
        *reinterpret_cast<float4*>(eout + ((size_t)(b*EE + e))*DD + q4) = z;
    }
}

// ---------------------------------------------------------------------------
// k_attn: per (b,i): logits = lrelu(s[j] + t[i] + u[b,i*N+j]) -> softmax over j
//         agg[b,i,:] = sum_j attn_j * zh[b,j,:]
__global__ void k_attn(const float* __restrict__ sI, const float* __restrict__ tI,
                       const float* __restrict__ u, const float* __restrict__ zh,
                       float* __restrict__ agg)
{
    int blk = blockIdx.x; int b = blk >> 7, i = blk & 127;
    int l = threadIdx.x;
    __shared__ float at[NN];
    float ti = tI[blk];
    float l0 = sI[b*NN + l]      + ti + u[b*EE + i*NN + l];
    float l1 = sI[b*NN + l + 64] + ti + u[b*EE + i*NN + l + 64];
    l0 = l0 >= 0.f ? l0 : 0.01f*l0;
    l1 = l1 >= 0.f ? l1 : 0.01f*l1;
    float mx = fmaxf(l0, l1);
#pragma unroll
    for (int off = 32; off; off >>= 1) mx = fmaxf(mx, __shfl_xor(mx, off));
    float e0 = expf(l0 - mx), e1 = expf(l1 - mx);
    float sm = e0 + e1;
#pragma unroll
    for (int off = 32; off; off >>= 1) sm += __shfl_xor(sm, off);
    float inv = 1.f / sm;
    at[l]      = e0 * inv;
    at[l + 64] = e1 * inv;
    __syncthreads();
    float acc = 0.f;
    for (int j = 0; j < NN; ++j) acc += at[j] * zh[(b*NN + j)*DD + l];
    agg[(b*NN + i)*DD + l] = acc;
}

// ---------------------------------------------------------------------------
// k_vbn: vertex BN (channel i over b,d) + residual + ELU
__global__ void k_vbn(const float* __restrict__ agg, const float* __restrict__ xres,
                      const float* __restrict__ gv, const float* __restrict__ bv,
                      float* __restrict__ xout)
{
    int i = blockIdx.x, t = threadIdx.x;
    float vals[8];
    float s1 = 0.f, s2 = 0.f;
#pragma unroll
    for (int q = 0; q < 8; ++q) {
        int m = t + 256*q; int b = m >> 6, d = m & 63;
        float v = agg[(b*NN + i)*DD + d];
        vals[q] = v; s1 += v; s2 += v*v;
    }
#pragma unroll
    for (int off = 1; off < 64; off <<= 1) {
        s1 += __shfl_xor(s1, off);
        s2 += __shfl_xor(s2, off);
    }
    __shared__ float r1[4], r2[4];
    int wv = t >> 6;
    if ((t & 63) == 0) { r1[wv] = s1; r2[wv] = s2; }
    __syncthreads();
    s1 = r1[0] + r1[1] + r1[2] + r1[3];
    s2 = r2[0] + r2[1] + r2[2] + r2[3];
    float mean  = s1 * (1.f/2048.f);
    float var   = s2 * (1.f/2048.f) - mean*mean;
    float scale = gv[i] * rsqrtf(var + EPSI);
    float shift = bv[i] - mean*scale;
#pragma unroll
    for (int q = 0; q < 8; ++q) {
        int m = t + 256*q; int b = m >> 6, d = m & 63;
        float v = vals[q]*scale + shift + xres[(b*NN + i)*DD + d];
        xout[(b*NN + i)*DD + d] = v > 0.f ? v : expm1f(v);
    }
}

// ---------------------------------------------------------------------------
extern "C" void kernel_launch(void* const* d_in, const int* in_sizes, int n_in,
                              void* d_out, int out_size, void* d_ws, size_t ws_size,
                              hipStream_t stream)
{
    const float* x    = (const float*)d_in[0];
    const float* edge = (const float*)d_in[1];
    const float* Wh1  = (const float*)d_in[2];
    const float* We1  = (const float*)d_in[3];
    const float* Wp1  = (const float*)d_in[4];
    const float* Wa1  = (const float*)d_in[5];
    const float* Wh2  = (const float*)d_in[6];
    const float* We2  = (const float*)d_in[7];
    const float* Wp2  = (const float*)d_in[8];
    const float* Wa2  = (const float*)d_in[9];
    const float* gv1  = (const float*)d_in[10];
    const float* bv1  = (const float*)d_in[11];
    const float* ge1  = (const float*)d_in[12];
    const float* be1  = (const float*)d_in[13];
    const float* gv2  = (const float*)d_in[14];
    const float* bv2  = (const float*)d_in[15];
    const float* ge2  = (const float*)d_in[16];
    const float* be2  = (const float*)d_in[17];

    float* xout = (float*)d_out;                    // (B,N,D)
    float* eout = (float*)d_out + BB*NN*DD;         // (B,E,D) — also layer-1 intermediate

    float* ws  = (float*)d_ws;
    float* M   = ws;  ws += DD*DD;
    float* wv  = ws;  ws += DD;
    float* zh  = ws;  ws += BB*NN*DD;
    float* Ps  = ws;  ws += BB*NN*DD;
    float* Pd  = ws;  ws += BB*NN*DD;
    float* sb  = ws;  ws += BB*NN;
    float* tb  = ws;  ws += BB*NN;
    float* ub  = ws;  ws += BB*EE;
    float* agg = ws;  ws += BB*NN*DD;
    float* x1  = ws;  ws += BB*NN*DD;   // total ~7.4 MB

    // ----- layer 1 -----
    k_fold<<<16, 256, 0, stream>>>(Wp1, We1, Wa1, M, wv);
    k_node<<<BB*NN, 64, 0, stream>>>(x, Wh1, Wp1, Wa1, zh, Ps, Pd, sb, tb);
    k_edge<<<EE/CH, 128, 0, stream>>>(edge, M, wv, Ps, Pd, ge1, be1, eout, ub);
    k_attn<<<BB*NN, 64, 0, stream>>>(sb, tb, ub, zh, agg);
    k_vbn<<<NN, 256, 0, stream>>>(agg, x, gv1, bv1, x1);
    // ----- layer 2 (k_edge reads/writes eout in place; a block reads only the
    //               rows it rewrites, and all reads precede its writes) -----
    k_fold<<<16, 256, 0, stream>>>(Wp2, We2, Wa2, M, wv);
    k_node<<<BB*NN, 64, 0, stream>>>(x1, Wh2, Wp2, Wa2, zh, Ps, Pd, sb, tb);
    k_edge<<<EE/CH, 128, 0, stream>>>(eout, M, wv, Ps, Pd, ge2, be2, eout, ub);
    k_attn<<<BB*NN, 64, 0, stream>>>(sb, tb, ub, zh, agg);
    k_vbn<<<NN, 256, 0, stream>>>(agg, x1, gv2, bv2, xout);
}

// Round 4
// 224.675 us; speedup vs baseline: 1.7807x; 1.2199x over previous
//
#include <hip/hip_runtime.h>
#include <math.h>

#define BB 32
#define NN 128
#define DD 64
#define EE (NN*NN)          // 16384
#define EPSI 1e-5f

typedef __attribute__((ext_vector_type(8))) short bf16x8;   // 8 bf16 (4 VGPRs)
typedef __attribute__((ext_vector_type(4))) float f32x4;

__device__ __forceinline__ short f2bf(float f) {
    union { float f; unsigned u; } v; v.f = f;
    unsigned u = v.u;
    unsigned r = (u + 0x7FFFu + ((u >> 16) & 1u)) >> 16;    // RNE
    return (short)r;
}
__device__ __forceinline__ float dot4(float4 a, float4 b) {
    return a.x*b.x + a.y*b.y + a.z*b.z + a.w*b.w;
}
__device__ __forceinline__ float elu(float v) {
    return v > 0.f ? v : __expf(v) - 1.f;     // v_exp_f32 path, not libm expm1f
}

// ---------------------------------------------------------------------------
// k_fold: Mbf[d][k] = bf16( sum_o Wp[d][128+o] * We[o][k] )  (fc_e folded into fc_proj)
//         w[k]      =       sum_o Wa[128+o]    * We[o][k]    (fc_e folded into attn_fc)
__global__ void k_fold(const float* __restrict__ Wp, const float* __restrict__ We,
                       const float* __restrict__ Wa,
                       short* __restrict__ Mbf, float* __restrict__ w)
{
    int t = blockIdx.x * 256 + threadIdx.x;   // 0..4095
    int d = t >> 6, k = t & 63;
    float acc = 0.f;
    for (int o = 0; o < DD; ++o)
        acc += Wp[d*192 + 128 + o] * We[o*DD + k];
    Mbf[d*DD + k] = f2bf(acc);
    if (d == 0) {
        float aw = 0.f;
        for (int o = 0; o < DD; ++o)
            aw += Wa[128 + o] * We[o*DD + k];
        w[k] = aw;
    }
}

// ---------------------------------------------------------------------------
// k_node: per (b,n) row: z_h = x @ Wh^T ; P_src = z_h @ Wp[:, :64]^T ;
//         P_dst = z_h @ Wp[:, 64:128]^T ; s = z_h . Wa[:64] ; t = z_h . Wa[64:128]
__global__ void k_node(const float* __restrict__ x, const float* __restrict__ Wh,
                       const float* __restrict__ Wp, const float* __restrict__ Wa,
                       float* __restrict__ zh, float* __restrict__ Ps,
                       float* __restrict__ Pd, float* __restrict__ sO,
                       float* __restrict__ tO)
{
    int row = blockIdx.x;          // b*N + n
    int d = threadIdx.x;           // 0..63
    __shared__ float xr[DD];
    __shared__ float zr[DD];
    xr[d] = x[row*DD + d];
    __syncthreads();
    float acc = 0.f;
#pragma unroll
    for (int k = 0; k < DD; ++k) acc += xr[k] * Wh[d*DD + k];
    zr[d] = acc;
    zh[row*DD + d] = acc;
    __syncthreads();
    float a0 = 0.f, a1 = 0.f;
#pragma unroll
    for (int o = 0; o < DD; ++o) {
        float z = zr[o];
        a0 += Wp[d*192 + o]      * z;
        a1 += Wp[d*192 + 64 + o] * z;
    }
    Ps[row*DD + d] = a0;
    Pd[row*DD + d] = a1;
    float sv = zr[d] * Wa[d];
    float tv = zr[d] * Wa[64 + d];
#pragma unroll
    for (int off = 32; off; off >>= 1) {
        sv += __shfl_xor(sv, off);
        tv += __shfl_xor(tv, off);
    }
    if (d == 0) { sO[row] = sv; tO[row] = tv; }
}

// ---------------------------------------------------------------------------
// k_edge v4 (bf16 MFMA, 1 wave / 1 e-channel):
//   z = edge @ M^T + Ps[b,j] + Pd[b,i]  -> BN(per-e over b,d) -> ELU
//   side output u[b,e] = edge . w  (fp32)
// Block = 64 threads = 32 rows (b=0..31, e fixed) x 64 cols, K=64 -> 16 MFMAs.
// B (=M^T, bf16) + w in registers; epilogue repacks C through 8.7 KB LDS;
// BN stats are a full-wave shfl reduce (channel == block).
__global__ __launch_bounds__(64, 4) void k_edge(
    const float* __restrict__ ein,   // (B,E,D)
    const short* __restrict__ Mbf,   // (D,D) bf16
    const float* __restrict__ wvec,  // (D)
    const float* __restrict__ Ps,    // (B,N,D)
    const float* __restrict__ Pd,    // (B,N,D)
    const float* __restrict__ ge, const float* __restrict__ be,
    float* __restrict__ eout, float* __restrict__ uout)
{
    __shared__ float zl[32][68];     // repack buffer, padded

    const int l  = threadIdx.x;      // 0..63
    const int lr = l & 15;
    const int lg = l >> 4;
    const int e  = blockIdx.x;
    const int i0 = e >> 7, j0 = e & 127;

    // ---- B fragments (M^T, already bf16) + w fragment (fp32) ----
    bf16x8 bfr[4][2];
#pragma unroll
    for (int n = 0; n < 4; ++n)
#pragma unroll
        for (int s = 0; s < 2; ++s)
            bfr[n][s] = *reinterpret_cast<const bf16x8*>(Mbf + (16*n + lr)*DD + s*32 + lg*8);
    float4 wlo[2], whi[2];
#pragma unroll
    for (int s = 0; s < 2; ++s) {
        wlo[s] = *reinterpret_cast<const float4*>(wvec + s*32 + lg*8);
        whi[s] = *reinterpret_cast<const float4*>(wvec + s*32 + lg*8 + 4);
    }

    f32x4 acc[2][4];
#pragma unroll
    for (int m = 0; m < 2; ++m)
#pragma unroll
        for (int n = 0; n < 4; ++n)
            acc[m][n] = (f32x4){0.f, 0.f, 0.f, 0.f};

    // ---- GEMM + u over 32 rows (b = 16m + lr) ----
#pragma unroll
    for (int m = 0; m < 2; ++m) {
        const int b = 16*m + lr;
        const float* rowp = ein + ((size_t)b*EE + e)*DD;
        const float4 a0lo = *reinterpret_cast<const float4*>(rowp +      lg*8);
        const float4 a0hi = *reinterpret_cast<const float4*>(rowp +      lg*8 + 4);
        const float4 a1lo = *reinterpret_cast<const float4*>(rowp + 32 + lg*8);
        const float4 a1hi = *reinterpret_cast<const float4*>(rowp + 32 + lg*8 + 4);
        // attention logit partial (fp32)
        float up = dot4(a0lo, wlo[0]) + dot4(a0hi, whi[0])
                 + dot4(a1lo, wlo[1]) + dot4(a1hi, whi[1]);
        up += __shfl_xor(up, 16);
        up += __shfl_xor(up, 32);
        if (lg == 0) uout[(size_t)b*EE + e] = up;
        // A fragments in bf16
        bf16x8 a0, a1;
        a0[0]=f2bf(a0lo.x); a0[1]=f2bf(a0lo.y); a0[2]=f2bf(a0lo.z); a0[3]=f2bf(a0lo.w);
        a0[4]=f2bf(a0hi.x); a0[5]=f2bf(a0hi.y); a0[6]=f2bf(a0hi.z); a0[7]=f2bf(a0hi.w);
        a1[0]=f2bf(a1lo.x); a1[1]=f2bf(a1lo.y); a1[2]=f2bf(a1lo.z); a1[3]=f2bf(a1lo.w);
        a1[4]=f2bf(a1hi.x); a1[5]=f2bf(a1hi.y); a1[6]=f2bf(a1hi.z); a1[7]=f2bf(a1hi.w);
#pragma unroll
        for (int n = 0; n < 4; ++n) {
            acc[m][n] = __builtin_amdgcn_mfma_f32_16x16x32_bf16(a0, bfr[n][0], acc[m][n], 0, 0, 0);
            acc[m][n] = __builtin_amdgcn_mfma_f32_16x16x32_bf16(a1, bfr[n][1], acc[m][n], 0, 0, 0);
        }
    }

    // ---- C fragments -> LDS (row = 16m + 4lg + q, col = 16n + lr) ----
#pragma unroll
    for (int m = 0; m < 2; ++m)
#pragma unroll
        for (int n = 0; n < 4; ++n)
#pragma unroll
            for (int q = 0; q < 4; ++q)
                zl[16*m + 4*lg + q][16*n + lr] = acc[m][n][q];
    __syncthreads();

    // ---- stats pass: z += Ps[b,j0] + Pd[b,i0] (written back), sum/sumsq ----
    const int q4 = lr*4;             // col (float) this thread covers
    float s1 = 0.f, s2 = 0.f;
#pragma unroll
    for (int it = 0; it < 8; ++it) {
        const int b = lg + 4*it;     // row == batch (e fixed)
        float4 z = *reinterpret_cast<float4*>(&zl[b][q4]);
        const float4 ps = *reinterpret_cast<const float4*>(Ps + (b*NN + j0)*DD + q4);
        const float4 pd = *reinterpret_cast<const float4*>(Pd + (b*NN + i0)*DD + q4);
        z.x += ps.x + pd.x; z.y += ps.y + pd.y;
        z.z += ps.z + pd.z; z.w += ps.w + pd.w;
        s1 += z.x + z.y + z.z + z.w;
        s2 += z.x*z.x + z.y*z.y + z.z*z.z + z.w*z.w;
        *reinterpret_cast<float4*>(&zl[b][q4]) = z;
    }
#pragma unroll
    for (int off = 1; off < 64; off <<= 1) {
        s1 += __shfl_xor(s1, off);
        s2 += __shfl_xor(s2, off);
    }
    const float mean  = s1 * (1.f/2048.f);
    const float var   = s2 * (1.f/2048.f) - mean*mean;
    const float sc = ge[e] * rsqrtf(var + EPSI);
    const float sh = be[e] - mean*sc;
    __syncthreads();

    // ---- normalize + ELU + store (each thread reads back its own writes) ----
#pragma unroll
    for (int it = 0; it < 8; ++it) {
        const int b = lg + 4*it;
        float4 z = *reinterpret_cast<float4*>(&zl[b][q4]);
        z.x = elu(z.x*sc + sh);
        z.y = elu(z.y*sc + sh);
        z.z = elu(z.z*sc + sh);
        z.w = elu(z.w*sc + sh);
        *reinterpret_cast<float4*>(eout + ((size_t)b*EE + e)*DD + q4) = z;
    }
}

// ---------------------------------------------------------------------------
// k_attn: per (b,i): logits = lrelu(s[j] + t[i] + u[b,i*N+j]) -> softmax over j
//         agg[b,i,:] = sum_j attn_j * zh[b,j,:]
__global__ void k_attn(const float* __restrict__ sI, const float* __restrict__ tI,
                       const float* __restrict__ u, const float* __restrict__ zh,
                       float* __restrict__ agg)
{
    int blk = blockIdx.x; int b = blk >> 7, i = blk & 127;
    int l = threadIdx.x;
    __shared__ float at[NN];
    float ti = tI[blk];
    float l0 = sI[b*NN + l]      + ti + u[b*EE + i*NN + l];
    float l1 = sI[b*NN + l + 64] + ti + u[b*EE + i*NN + l + 64];
    l0 = l0 >= 0.f ? l0 : 0.01f*l0;
    l1 = l1 >= 0.f ? l1 : 0.01f*l1;
    float mx = fmaxf(l0, l1);
#pragma unroll
    for (int off = 32; off; off >>= 1) mx = fmaxf(mx, __shfl_xor(mx, off));
    float e0 = __expf(l0 - mx), e1 = __expf(l1 - mx);
    float sm = e0 + e1;
#pragma unroll
    for (int off = 32; off; off >>= 1) sm += __shfl_xor(sm, off);
    float inv = 1.f / sm;
    at[l]      = e0 * inv;
    at[l + 64] = e1 * inv;
    __syncthreads();
    float acc = 0.f;
    for (int j = 0; j < NN; ++j) acc += at[j] * zh[(b*NN + j)*DD + l];
    agg[(b*NN + i)*DD + l] = acc;
}

// ---------------------------------------------------------------------------
// k_vbn: vertex BN (channel i over b,d) + residual + ELU
__global__ void k_vbn(const float* __restrict__ agg, const float* __restrict__ xres,
                      const float* __restrict__ gv, const float* __restrict__ bv,
                      float* __restrict__ xout)
{
    int i = blockIdx.x, t = threadIdx.x;
    float vals[8];
    float s1 = 0.f, s2 = 0.f;
#pragma unroll
    for (int q = 0; q < 8; ++q) {
        int m = t + 256*q; int b = m >> 6, d = m & 63;
        float v = agg[(b*NN + i)*DD + d];
        vals[q] = v; s1 += v; s2 += v*v;
    }
#pragma unroll
    for (int off = 1; off < 64; off <<= 1) {
        s1 += __shfl_xor(s1, off);
        s2 += __shfl_xor(s2, off);
    }
    __shared__ float r1[4], r2[4];
    int wv = t >> 6;
    if ((t & 63) == 0) { r1[wv] = s1; r2[wv] = s2; }
    __syncthreads();
    s1 = r1[0] + r1[1] + r1[2] + r1[3];
    s2 = r2[0] + r2[1] + r2[2] + r2[3];
    float mean  = s1 * (1.f/2048.f);
    float var   = s2 * (1.f/2048.f) - mean*mean;
    float scale = gv[i] * rsqrtf(var + EPSI);
    float shift = bv[i] - mean*scale;
#pragma unroll
    for (int q = 0; q < 8; ++q) {
        int m = t + 256*q; int b = m >> 6, d = m & 63;
        float v = vals[q]*scale + shift + xres[(b*NN + i)*DD + d];
        xout[(b*NN + i)*DD + d] = v > 0.f ? v : __expf(v) - 1.f;
    }
}

// ---------------------------------------------------------------------------
extern "C" void kernel_launch(void* const* d_in, const int* in_sizes, int n_in,
                              void* d_out, int out_size, void* d_ws, size_t ws_size,
                              hipStream_t stream)
{
    const float* x    = (const float*)d_in[0];
    const float* edge = (const float*)d_in[1];
    const float* Wh1  = (const float*)d_in[2];
    const float* We1  = (const float*)d_in[3];
    const float* Wp1  = (const float*)d_in[4];
    const float* Wa1  = (const float*)d_in[5];
    const float* Wh2  = (const float*)d_in[6];
    const float* We2  = (const float*)d_in[7];
    const float* Wp2  = (const float*)d_in[8];
    const float* Wa2  = (const float*)d_in[9];
    const float* gv1  = (const float*)d_in[10];
    const float* bv1  = (const float*)d_in[11];
    const float* ge1  = (const float*)d_in[12];
    const float* be1  = (const float*)d_in[13];
    const float* gv2  = (const float*)d_in[14];
    const float* bv2  = (const float*)d_in[15];
    const float* ge2  = (const float*)d_in[16];
    const float* be2  = (const float*)d_in[17];

    float* xout = (float*)d_out;                    // (B,N,D)
    float* eout = (float*)d_out + BB*NN*DD;         // (B,E,D) — also layer-1 intermediate

    float* ws  = (float*)d_ws;
    short* Mbf = (short*)ws;  ws += DD*DD/2;        // bf16 M^T source (8 KB)
    float* wv  = ws;  ws += DD;
    float* zh  = ws;  ws += BB*NN*DD;
    float* Ps  = ws;  ws += BB*NN*DD;
    float* Pd  = ws;  ws += BB*NN*DD;
    float* sb  = ws;  ws += BB*NN;
    float* tb  = ws;  ws += BB*NN;
    float* ub  = ws;  ws += BB*EE;
    float* agg = ws;  ws += BB*NN*DD;
    float* x1  = ws;  ws += BB*NN*DD;   // total ~7.4 MB

    // ----- layer 1 -----
    k_fold<<<16, 256, 0, stream>>>(Wp1, We1, Wa1, Mbf, wv);
    k_node<<<BB*NN, 64, 0, stream>>>(x, Wh1, Wp1, Wa1, zh, Ps, Pd, sb, tb);
    k_edge<<<EE, 64, 0, stream>>>(edge, Mbf, wv, Ps, Pd, ge1, be1, eout, ub);
    k_attn<<<BB*NN, 64, 0, stream>>>(sb, tb, ub, zh, agg);
    k_vbn<<<NN, 256, 0, stream>>>(agg, x, gv1, bv1, x1);
    // ----- layer 2 (k_edge reads/writes eout in place; each block owns its
    //               e-column exclusively and all A-loads are consumed by the
    //               MFMAs before the first store) -----
    k_fold<<<16, 256, 0, stream>>>(Wp2, We2, Wa2, Mbf, wv);
    k_node<<<BB*NN, 64, 0, stream>>>(x1, Wh2, Wp2, Wa2, zh, Ps, Pd, sb, tb);
    k_edge<<<EE, 64, 0, stream>>>(eout, Mbf, wv, Ps, Pd, ge2, be2, eout, ub);
    k_attn<<<BB*NN, 64, 0, stream>>>(sb, tb, ub, zh, agg);
    k_vbn<<<NN, 256, 0, stream>>>(agg, x1, gv2, bv2, xout);
}